// Round 8
// baseline (649.737 us; speedup 1.0000x reference)
//
#include <hip/hip_runtime.h>

#define DIM    192
#define HEADS  6
#define NTOK   49
#define NWIN   64

typedef __attribute__((ext_vector_type(8))) short short8;
typedef __attribute__((ext_vector_type(4))) float f32x4;

// LDS strides (elements). bf16 strides keep ds_read_b128 16B-aligned
// (stride*2 % 16 == 0); bank patterns are 2-way max (free, m136).
#define XS 200   // sx / kstage / sq row stride
#define VS 56    // sv (V^T) row stride: 49 real tokens + 7 pad
#define PS 72    // P row stride

// LDS carve (single ushort array; aliasing is load-bearing, order matters):
//  [0,9800)        K rows 0-48 (XS)          | phase0/1: sx rows 0-48
//  [9800,14408)    P0 (64xPS)                | sx rows 49-63 end at 12800;
//                                              K-epilogue garbage rows 49-63
//                                              scribble here (finite, pre-P)
//  [14408,19016)   P1 (64xPS)
//  [19016,28816)   sq: Q (scaled) -> O, rows 0-48 only; reads of rows 49-63
//                  fall into sv (finite bf16, D-rows discarded)
//  [28816,39568)   sv: V^T 192 x VS
//  [39568,39632)   tail pad (last V row's token-56..63 overflow reads)
// NaN-safety: garbage A-rows only pollute discarded D-rows; garbage B-cols
// only pollute masked lanes; V pad tokens 49-55 are finite because x pad
// rows are zeroed in phase 0 (P pads are exactly 0.0, but 0*NaN=NaN).
#define P0_EOFF 9800
#define P1_EOFF 14408
#define SQ_EOFF 19016
#define SV_EOFF 28816
#define LDS_USHORTS 39632   // 79264 B <= 81920 -> 2 blocks/CU

#define BIAS_ELEMS (HEADS * NTOK * NTOK)             // 14406 floats
#define WQKV_SOFF   28864                            // ushort offset in ws
#define WQKV_ELEMS  (3 * DIM * DIM)                  // 110592
#define WPROJ_SOFF  (WQKV_SOFF + WQKV_ELEMS)
#define WPROJ_ELEMS (DIM * DIM)                      // 36864
#define CMB_BOFF    ((size_t)(WPROJ_SOFF + WPROJ_ELEMS) * 2)   // 352640 B
#define CMB2_ELEMS  (NWIN * HEADS * NTOK * 64)       // 1204224 floats (4.82 MB)

__device__ __forceinline__ unsigned short f2bf(float f) {
    unsigned int u = __float_as_uint(f);
    u += 0x7FFFu + ((u >> 16) & 1u);   // round-to-nearest-even
    return (unsigned short)(u >> 16);
}

// ---------------- K1: bias gather + bf16 weights + padded cmb2 table ----------------
__global__ void wa_prep_kernel(const int* __restrict__ rpi,
                               const float* __restrict__ rpb,
                               const float* __restrict__ qkv_w,
                               const float* __restrict__ proj_w,
                               const float* __restrict__ maskp,
                               float* __restrict__ bias,
                               unsigned short* __restrict__ wqkv,
                               unsigned short* __restrict__ wproj,
                               float* __restrict__ cmb2) {
    __shared__ int is64_s;
    if (threadIdx.x < 64) {
        int z = (rpi[2 * (int)threadIdx.x + 1] == 0) ? 1 : 0;
        unsigned long long b = __ballot(z);
        if (threadIdx.x == 0) is64_s = (__popcll(b) >= 48) ? 1 : 0;
    }
    __syncthreads();
    const int is64 = is64_s;
    const int base3 = BIAS_ELEMS + WQKV_ELEMS + WPROJ_ELEMS;
    const int total = base3 + (cmb2 ? CMB2_ELEMS : 0);
    for (int idx = blockIdx.x * blockDim.x + threadIdx.x; idx < total;
         idx += gridDim.x * blockDim.x) {
        if (idx < BIAS_ELEMS) {
            int h  = idx / (NTOK * NTOK);
            int nm = idx - h * (NTOK * NTOK);
            int r  = is64 ? rpi[2 * nm] : rpi[nm];
            bias[idx] = rpb[r * HEADS + h];
        } else if (idx < BIAS_ELEMS + WQKV_ELEMS) {
            int i = idx - BIAS_ELEMS;
            wqkv[i] = f2bf(qkv_w[i]);
        } else if (idx < base3) {
            int i = idx - BIAS_ELEMS - WQKV_ELEMS;
            wproj[i] = f2bf(proj_w[i]);
        } else {
            int i2  = idx - base3;
            int win = i2 / (HEADS * NTOK * 64);
            int rem = i2 - win * (HEADS * NTOK * 64);
            int h   = rem / (NTOK * 64);
            int rm2 = rem - h * (NTOK * 64);
            int q   = rm2 >> 6;
            int k   = rm2 & 63;
            float v = 0.f;
            if (k < NTOK) {
                int nm = q * NTOK + k;
                int r  = is64 ? rpi[2 * nm] : rpi[nm];
                v = rpb[r * HEADS + h] + maskp[win * (NTOK * NTOK) + nm];
            }
            cmb2[i2] = v;
        }
    }
}

// ---------------- K2: fused QKV + attention + output projection ----------------
// One block per window, 2 blocks/CU. Register model (R1-R7): VGPR_Count
// excludes AGPRs; waves/EU = floor(512/(V+A)); launch_bounds 2nd arg = min
// waves/EU (cap 512/N). R7 natural demand ~80 -> fits the 128 cap, no spill.
//
// HEAD LOOP (paired, R8): 3 groups of 2 heads. Per group:
//   A: all 8 waves swapped-QK^T + in-register softmax (wave>=4 -> head 2g+1,
//      two P buffers), B: P writes, C: all 8 waves PV (wave's q-tile x 2
//      V-col-tiles) -> O into sq cols of its head. 2 barriers/group (6 total,
//      was 12) with 2x independent work per barrier interval.
template <bool CMB>
__global__ __launch_bounds__(512, 4)
void wa_attn_kernel(const float* __restrict__ x,
                    const float* __restrict__ maskp,
                    const unsigned short* __restrict__ wqkv,
                    const float* __restrict__ qkv_b,
                    const float* __restrict__ biasp,
                    const unsigned short* __restrict__ wproj,
                    const float* __restrict__ proj_b,
                    const float* __restrict__ cmbp,
                    float* __restrict__ out) {
    __shared__ __attribute__((aligned(16))) unsigned short lds[LDS_USHORTS];
    unsigned short* sx     = lds;              // phase 0/1 staging (rows 0-63)
    unsigned short* kstage = lds;              // head loop: K rows 0-48
    unsigned short* sq     = lds + SQ_EOFF;    // Q (scaled) -> O, rows 0-48
    unsigned short* sv     = lds + SV_EOFF;    // V^T

    const int tid  = threadIdx.x;
    const int wave = tid >> 6;
    const int lane = tid & 63;
    const int quad = lane >> 4;
    const int l16  = lane & 15;
    const int bw   = blockIdx.x;
    const int win  = bw & (NWIN - 1);
    const float scale = 0.17677669529663687f;

    // ---- phase 0: stage x window fp32 -> bf16 LDS, zero pad rows 49..63 ----
    // Pad zeroing is REQUIRED: it keeps V pad tokens finite (P=0 * NaN = NaN).
    {
        const float4* xw = (const float4*)(x + (size_t)bw * (NTOK * DIM));
        for (int idx = tid; idx < NTOK * DIM / 4; idx += 512) {
            int row = idx / 48, c4 = idx - row * 48;
            float4 v = xw[idx];
            unsigned int lo = (unsigned int)f2bf(v.x) | ((unsigned int)f2bf(v.y) << 16);
            unsigned int hi = (unsigned int)f2bf(v.z) | ((unsigned int)f2bf(v.w) << 16);
            *(uint2*)&sx[row * XS + c4 * 4] = make_uint2(lo, hi);
        }
        for (int idx = tid; idx < 15 * 24; idx += 512) {
            int row = 49 + idx / 24, c8 = idx - (idx / 24) * 24;
            *(uint4*)&sx[row * XS + c8 * 8] = make_uint4(0, 0, 0, 0);
        }
    }
    __syncthreads();

    // ---- phase 1: QKV = X * Wqkv^T + b, CHUNKED (Q, V, then K) ----
    // acc[3][2] = 24 AGPR per chunk; static unroll mandatory (scratch demotion).
    // Q epilogue guards rows<49 (unguarded rows would race V's sv writes);
    // V epilogue guards mbase<56 (VS=56 row width); K unguarded (rows 49-63
    // scribble the P0 region, overwritten before first read as P).
    {
        const int wm = wave >> 2;
        const int wn = wave & 3;
        #pragma unroll
        for (int cc = 0; cc < 3; ++cc) {
            const int c = (cc == 0) ? 0 : (cc == 1 ? 2 : 1);   // Q, V, K(last)
            f32x4 acc[3][2];
            #pragma unroll
            for (int r = 0; r < 3; ++r)
                #pragma unroll
                for (int mi = 0; mi < 2; ++mi) acc[r][mi] = (f32x4){0.f, 0.f, 0.f, 0.f};
            for (int k0 = 0; k0 < DIM; k0 += 32) {
                short8 af[2];
                #pragma unroll
                for (int mi = 0; mi < 2; ++mi)
                    af[mi] = *(const short8*)&sx[((wm * 2 + mi) * 16 + l16) * XS + k0 + quad * 8];
                #pragma unroll
                for (int r = 0; r < 3; ++r) {
                    int n0 = c * 192 + (wn + 4 * r) * 16;
                    short8 bf = *(const short8*)(wqkv + (n0 + l16) * DIM + k0 + quad * 8);
                    #pragma unroll
                    for (int mi = 0; mi < 2; ++mi)
                        acc[r][mi] = __builtin_amdgcn_mfma_f32_16x16x32_bf16(af[mi], bf, acc[r][mi], 0, 0, 0);
                }
            }
            if (c == 1) __syncthreads();   // all sx reads done before K overwrites it
            #pragma unroll
            for (int r = 0; r < 3; ++r) {
                int ccol = (wn + 4 * r) * 16 + l16;
                float cb = qkv_b[c * 192 + ccol];
                #pragma unroll
                for (int mi = 0; mi < 2; ++mi) {
                    int mbase = (wm * 2 + mi) * 16 + quad * 4;
                    if (c == 2) {
                        // V^T: 4 rr = consecutive tokens; skip token rows >= 56
                        if (mbase < 56) {
                            unsigned int lo = (unsigned int)f2bf(acc[r][mi][0] + cb) |
                                              ((unsigned int)f2bf(acc[r][mi][1] + cb) << 16);
                            unsigned int hi = (unsigned int)f2bf(acc[r][mi][2] + cb) |
                                              ((unsigned int)f2bf(acc[r][mi][3] + cb) << 16);
                            *(uint2*)&sv[ccol * VS + mbase] = make_uint2(lo, hi);
                        }
                    } else if (c == 1) {
                        #pragma unroll
                        for (int rr = 0; rr < 4; ++rr)
                            kstage[(mbase + rr) * XS + ccol] = f2bf(acc[r][mi][rr] + cb);
                    } else {
                        // Q: fold QK scale; guard rows<49 (sq is 49 rows)
                        #pragma unroll
                        for (int rr = 0; rr < 4; ++rr)
                            if (mbase + rr < NTOK)
                                sq[(mbase + rr) * XS + ccol] = f2bf((acc[r][mi][rr] + cb) * scale);
                    }
                }
            }
        }
    }
    __syncthreads();

    // ---- head loop: 3 groups x 2 heads ----
    const int hh   = wave >> 2;          // 0: even head, 1: odd head
    const int qt   = wave & 3;           // q-tile (also PV m-tile)
    const int q    = qt * 16 + l16;
    const int qv   = (q < NTOK);
    unsigned short* Pb = lds + (hh ? P1_EOFF : P0_EOFF);

    for (int g = 0; g < 3; ++g) {
        const int head = 2 * g + hh;
        // ---- A: S^T = K Q^T (swapped MFMA), in-register softmax ----
        unsigned int pw[4][2];
        {
            short8 bq = *(const short8*)&sq[(qt * 16 + l16) * XS + head * 32 + quad * 8];
            f32x4 d[4];
            #pragma unroll
            for (int kt = 0; kt < 4; ++kt) {
                short8 ak = *(const short8*)&kstage[(kt * 16 + l16) * XS + head * 32 + quad * 8];
                d[kt] = __builtin_amdgcn_mfma_f32_16x16x32_bf16(ak, bq, (f32x4){0.f, 0.f, 0.f, 0.f}, 0, 0, 0);
            }
            float s[4][4];
            float m = -1e30f;
            #pragma unroll
            for (int kt = 0; kt < 4; ++kt) {
                int kbase = kt * 16 + quad * 4;
                if (CMB) {
                    const int qc = qv ? q : (NTOK - 1);
                    float4 c4 = *(const float4*)(cmbp + (((size_t)(win * HEADS + head)) * NTOK + qc) * 64 + kbase);
                    const float* c4p = (const float*)&c4;
                    #pragma unroll
                    for (int rr = 0; rr < 4; ++rr) {
                        int k = kbase + rr;
                        s[kt][rr] = (k < NTOK && qv) ? d[kt][rr] + c4p[rr] : -30000.f;
                        m = fmaxf(m, s[kt][rr]);
                    }
                } else {
                    const float* bh = biasp + head * (NTOK * NTOK);
                    const float* mw = maskp + win * (NTOK * NTOK);
                    #pragma unroll
                    for (int rr = 0; rr < 4; ++rr) {
                        int k = kbase + rr;
                        float v = -30000.f;
                        if (k < NTOK && qv) v = d[kt][rr] + bh[q * NTOK + k] + mw[q * NTOK + k];
                        s[kt][rr] = v;
                        m = fmaxf(m, v);
                    }
                }
            }
            m = fmaxf(m, __shfl_xor(m, 16));
            m = fmaxf(m, __shfl_xor(m, 32));
            float p[4][4];
            float sum = 0.f;
            #pragma unroll
            for (int kt = 0; kt < 4; ++kt)
                #pragma unroll
                for (int rr = 0; rr < 4; ++rr) {
                    p[kt][rr] = __expf(s[kt][rr] - m);
                    sum += p[kt][rr];
                }
            sum += __shfl_xor(sum, 16);
            sum += __shfl_xor(sum, 32);
            float si = 1.f / sum;
            #pragma unroll
            for (int kt = 0; kt < 4; ++kt) {
                pw[kt][0] = (unsigned int)f2bf(p[kt][0] * si) | ((unsigned int)f2bf(p[kt][1] * si) << 16);
                pw[kt][1] = (unsigned int)f2bf(p[kt][2] * si) | ((unsigned int)f2bf(p[kt][3] * si) << 16);
            }
        }
        __syncthreads();   // A done (incl. all K/Q/P-garbage reads)
        // ---- B: write normalized bf16 P ----
        if (qv) {
            #pragma unroll
            for (int kt = 0; kt < 4; ++kt)
                *(uint2*)&Pb[q * PS + kt * 16 + quad * 4] = make_uint2(pw[kt][0], pw[kt][1]);
        }
        __syncthreads();   // P(2g), P(2g+1) visible
        // ---- C: O = P V -> bf16 into sq cols [32*head, 32*head+32) ----
        // No trailing barrier: next A reads disjoint sq cols / K rows; next
        // B's P writes are ordered by next A's barrier.
        #pragma unroll
        for (int tt = 0; tt < 2; ++tt) {
            f32x4 o = {0.f, 0.f, 0.f, 0.f};
            #pragma unroll
            for (int k0 = 0; k0 < 64; k0 += 32) {
                short8 ap = *(const short8*)&Pb[(qt * 16 + l16) * PS + k0 + quad * 8];
                short8 bv = *(const short8*)&sv[(head * 32 + tt * 16 + l16) * VS + k0 + quad * 8];
                o = __builtin_amdgcn_mfma_f32_16x16x32_bf16(ap, bv, o, 0, 0, 0);
            }
            #pragma unroll
            for (int rr = 0; rr < 4; ++rr) {
                int i = qt * 16 + quad * 4 + rr;
                if (i < NTOK)
                    sq[i * XS + head * 32 + tt * 16 + l16] = f2bf(o[rr]);
            }
        }
    }
    __syncthreads();

    // ---- phase 3: fused output projection  out = O @ proj_w^T + proj_b ----
    // A-rows 49-63 read sv data (finite) -> garbage D rows, discarded.
    {
        const int mh = wave >> 2;
        const int wv = wave & 3;
        f32x4 pacc[3][2];
        #pragma unroll
        for (int r = 0; r < 3; ++r)
            #pragma unroll
            for (int mi = 0; mi < 2; ++mi) pacc[r][mi] = (f32x4){0.f, 0.f, 0.f, 0.f};
        for (int k0 = 0; k0 < DIM; k0 += 32) {
            short8 af[2];
            #pragma unroll
            for (int mi = 0; mi < 2; ++mi)
                af[mi] = *(const short8*)&sq[((mh * 2 + mi) * 16 + l16) * XS + k0 + quad * 8];
            #pragma unroll
            for (int r = 0; r < 3; ++r) {
                int n0 = (wv + 4 * r) * 16;
                short8 bf = *(const short8*)(wproj + (n0 + l16) * DIM + k0 + quad * 8);
                #pragma unroll
                for (int mi = 0; mi < 2; ++mi)
                    pacc[r][mi] = __builtin_amdgcn_mfma_f32_16x16x32_bf16(af[mi], bf, pacc[r][mi], 0, 0, 0);
            }
        }
        #pragma unroll
        for (int r = 0; r < 3; ++r) {
            int n0 = (wv + 4 * r) * 16;
            float cb = proj_b[n0 + l16];
            #pragma unroll
            for (int mi = 0; mi < 2; ++mi) {
                #pragma unroll
                for (int rr = 0; rr < 4; ++rr) {
                    int m = (mh * 2 + mi) * 16 + quad * 4 + rr;
                    if (m < NTOK)
                        out[((size_t)bw * NTOK + m) * DIM + n0 + l16] = pacc[r][mi][rr] + cb;
                }
            }
        }
    }
}

extern "C" void kernel_launch(void* const* d_in, const int* in_sizes, int n_in,
                              void* d_out, int out_size, void* d_ws, size_t ws_size,
                              hipStream_t stream) {
    const float* x      = (const float*)d_in[0];
    const int*   rpi    = (const int*)d_in[1];
    const float* maskp  = (const float*)d_in[2];
    const float* qkv_w  = (const float*)d_in[3];
    const float* qkv_b  = (const float*)d_in[4];
    const float* proj_w = (const float*)d_in[5];
    const float* proj_b = (const float*)d_in[6];
    const float* rpb    = (const float*)d_in[7];
    float* out = (float*)d_out;

    float* bias = (float*)d_ws;
    unsigned short* wqkv  = (unsigned short*)d_ws + WQKV_SOFF;
    unsigned short* wproj = (unsigned short*)d_ws + WPROJ_SOFF;
    float* cmb2 = nullptr;                       // 4.82 MB padded bias+mask table
    if (ws_size >= CMB_BOFF + (size_t)CMB2_ELEMS * 4)
        cmb2 = (float*)((char*)d_ws + CMB_BOFF);

    wa_prep_kernel<<<640, 256, 0, stream>>>(rpi, rpb, qkv_w, proj_w, maskp,
                                            bias, wqkv, wproj, cmb2);
    if (cmb2)
        wa_attn_kernel<true><<<4096, 512, 0, stream>>>(x, maskp, wqkv, qkv_b, bias,
                                                       wproj, proj_b, cmb2, out);
    else
        wa_attn_kernel<false><<<4096, 512, 0, stream>>>(x, maskp, wqkv, qkv_b, bias,
                                                        wproj, proj_b, nullptr, out);
}